// Round 11
// baseline (152.320 us; speedup 1.0000x reference)
//
#include <hip/hip_runtime.h>
#include <hip/hip_fp16.h>

#define R_ 3
#define D_ 7            // 2R+1
#define W_ 49
#define N_ 128
#define K_ 131
#define C_ 21
#define B_ 2
#define NN (N_ * N_)
#define TILE 16                 // 16x16 pixel tile, 1 thread per pixel
#define PATCH (TILE + 2 * R_)   // 22
#define PSTR 24                 // LDS row stride (float2 pairs)
#define NELEM (PATCH * PATCH)   // 484 staged elements
#define LDSP (PATCH * PSTR + 8) // 536 pairs (spare write slot at 532)
#define KC 8                    // k-chunks per tile
#define KCHUNK ((K_ + KC - 1) / KC)    // 17

typedef __fp16 h2 __attribute__((ext_vector_type(2)));

// Affinity: per-pixel 7x7 window softmax per channel, weighted by cp[k].
// exp(|c-n|) = max(Ec*EnInv, En*EcInv), (E,Einv) pairs staged per element
// (E = exp2(f*mask*log2e)). ONE thread per pixel owns all 49 taps: with
// packed-f16 ex/Aacc (28 h2 each = 56 VGPRs) this fits without AGPR spill
// (impossible in fp32 - R3's lesson). No shfl, no lane-split phantom taps:
// the 4th h2 of each row packs (t6, 0.0f) so no masking hacks are needed.
// OOB neighbors stage (0,0) -> tap 0; unmasked neighbors stage (1,1) ->
// tap exp(|c|), matching the reference. Aout [B][W][NN], atomics over KC.
__global__ __launch_bounds__(256, 4) void rwn_affinity(
    const float* __restrict__ feats,   // [B,K,N,N]
    const int*   __restrict__ mask,    // [B,N,N]
    const float* __restrict__ cp,      // [K]
    float* __restrict__ Aout)          // [B,W,NN] (pre-zeroed)
{
    __shared__ float2 patch2[LDSP];

    const int tile = blockIdx.x;           // 0..63 (8x8 tiles of 16x16)
    const int kc   = blockIdx.y;
    const int b    = blockIdx.z;
    const int tr = tile >> 3, tc = tile & 7;
    const int ti0 = tr * TILE, tj0 = tc * TILE;

    const int tid = threadIdx.x;
    const int ti = tid >> 4;               // 0..15
    const int tj = tid & 15;               // 0..15
    const int gi = ti0 + ti, gj = tj0 + tj;

    // ---- hoisted staging setup: thread owns elements tid and 256+tid ----
    const float LOG2E = 1.4426950408889634f;
    int   soff[2];      // clamped global offset
    float swt[2];       // in-bounds * mask * log2e
    float ozw[2];       // 0 for OOB (store zero pair), 1 otherwise
    int   slds[2];      // pair index in LDS
    #pragma unroll
    for (int r = 0; r < 2; ++r) {
        int e = tid + r * 256;
        bool act = (e < NELEM);
        int pr = e / PATCH, pc = e - pr * PATCH;
        int mi = ti0 + pr - R_, mj = tj0 + pc - R_;
        bool inb = act && mi >= 0 && mi < N_ && mj >= 0 && mj < N_;
        int cmi = mi < 0 ? 0 : (mi > N_ - 1 ? N_ - 1 : mi);
        int cmj = mj < 0 ? 0 : (mj > N_ - 1 ? N_ - 1 : mj);
        soff[r] = cmi * N_ + cmj;
        swt[r]  = inb ? ((float)mask[b * NN + soff[r]] * LOG2E) : 0.f;
        ozw[r]  = inb ? 1.f : 0.f;
        slds[r] = act ? (pr * PSTR + pc) : (PATCH * PSTR + 4);  // spare slot
    }

    const int cbase = ti * PSTR + tj;      // pair addr of (pixel - (3,3))

    h2 Aacc[28];
    #pragma unroll
    for (int i = 0; i < 28; ++i) Aacc[i] = (h2){(__fp16)0.f, (__fp16)0.f};

    const int k0 = kc * KCHUNK;
    const int k1 = (k0 + KCHUNK < K_) ? (k0 + KCHUNK) : K_;
    const float* fb = feats + (size_t)b * K_ * NN;

    // zero-init all LDS pairs once: pad cols 22,23 / spare slot stay 0 forever
    for (int e = tid; e < LDSP; e += 256) patch2[e] = make_float2(0.f, 0.f);

    // software prefetch of first k (pre = f * mask * log2e)
    const float* fk0 = fb + (size_t)k0 * NN;
    float pre0 = fk0[soff[0]] * swt[0];
    float pre1 = fk0[soff[1]] * swt[1];

    __syncthreads();

    for (int k = k0; k < k1; ++k) {
        patch2[slds[0]] = make_float2(ozw[0] * exp2f(pre0), ozw[0] * exp2f(-pre0));
        patch2[slds[1]] = make_float2(ozw[1] * exp2f(pre1), ozw[1] * exp2f(-pre1));
        // prefetch next k while this one computes
        float n0 = 0.f, n1 = 0.f;
        if (k + 1 < k1) {
            const float* fn = fb + (size_t)(k + 1) * NN;
            n0 = fn[soff[0]] * swt[0];
            n1 = fn[soff[1]] * swt[1];
        }
        __syncthreads();

        const float2 cpair = patch2[cbase + R_ * PSTR + R_];
        h2 ex[28];
        float dsum = 0.f;
        #pragma unroll
        for (int u = 0; u < D_; ++u) {
            const int rb = cbase + u * PSTR;
            float t0 = 0.f, t1 = 0.f, t2 = 0.f, t3 = 0.f;
            float t4 = 0.f, t5 = 0.f, t6 = 0.f;
            {
                const float2 a0 = patch2[rb + 0];
                const float2 a1 = patch2[rb + 1];
                const float2 a2 = patch2[rb + 2];
                const float2 a3 = patch2[rb + 3];
                const float2 a4 = patch2[rb + 4];
                const float2 a5 = patch2[rb + 5];
                const float2 a6 = patch2[rb + 6];
                t0 = fmaxf(cpair.x * a0.y, a0.x * cpair.y);
                t1 = fmaxf(cpair.x * a1.y, a1.x * cpair.y);
                t2 = fmaxf(cpair.x * a2.y, a2.x * cpair.y);
                t3 = fmaxf(cpair.x * a3.y, a3.x * cpair.y);
                t4 = fmaxf(cpair.x * a4.y, a4.x * cpair.y);
                t5 = fmaxf(cpair.x * a5.y, a5.x * cpair.y);
                t6 = fmaxf(cpair.x * a6.y, a6.x * cpair.y);
            }
            dsum += ((t0 + t1) + (t2 + t3)) + ((t4 + t5) + t6);
            ex[u * 4 + 0] = __builtin_amdgcn_cvt_pkrtz(t0, t1);
            ex[u * 4 + 1] = __builtin_amdgcn_cvt_pkrtz(t2, t3);
            ex[u * 4 + 2] = __builtin_amdgcn_cvt_pkrtz(t4, t5);
            ex[u * 4 + 3] = __builtin_amdgcn_cvt_pkrtz(t6, 0.f);
        }
        const float scale = cp[k] * __frcp_rn(dsum);   // dsum >= 1 (center tap)
        const h2 s2 = __builtin_amdgcn_cvt_pkrtz(scale, scale);
        #pragma unroll
        for (int m = 0; m < 28; ++m) Aacc[m] = ex[m] * s2 + Aacc[m];
        __syncthreads();

        pre0 = n0; pre1 = n1;
    }

    if (mask[b * NN + gi * N_ + gj] != 0) {
        const int pixg = gi * N_ + gj;
        float* ab = Aout + (size_t)b * W_ * NN + pixg;
        #pragma unroll
        for (int u = 0; u < D_; ++u) {
            #pragma unroll
            for (int m = 0; m < 4; ++m) {
                const h2 tv = Aacc[u * 4 + m];
                atomicAdd(ab + (u * D_ + 2 * m) * NN, (float)tv[0]);
                if (m < 3)   // 4th pair's second slot is the 0.0 filler
                    atomicAdd(ab + (u * D_ + 2 * m + 1) * NN, (float)tv[1]);
            }
        }
    }
}

// Gather: out[b,q,c] = sum_w A[b,w,p]*x2[b,c,p], p=q-(u-3,v-3), w=u*7+v.
// Block = 32 q x 8 w-groups (256 thr) -> 1024 blocks = 4+ blocks/CU for
// latency hiding (was 2). wg owns u=wg (wg=7 idle in taps). 21 c-accumulators
// in registers; LDS reduce over 8 planes; contiguous store.
#define GQ 32     // q's per block
#define RSTR 22   // LDS reduce stride
__global__ __launch_bounds__(256, 4) void rwn_gather(
    const float* __restrict__ Aarr,  // [B,W,NN]
    const float* __restrict__ x2,    // [B,C,NN]
    float* __restrict__ out)         // [B,NN,C]
{
    __shared__ float red[8 * GQ * RSTR];   // 22528 B

    const int q0 = blockIdx.x * GQ;
    const int b  = blockIdx.y;
    const int tid = threadIdx.x;
    const int qh = tid & (GQ - 1);   // lane -> consecutive q (coalesced)
    const int wg = tid >> 5;         // w-group = u (uniform per 32-lane half)
    const int q = q0 + qh;
    const int i = q >> 7, j = q & (N_ - 1);

    const float* Ab = Aarr + (size_t)b * W_ * NN;
    const float* xb = x2 + (size_t)b * C_ * NN;

    float acc[C_];
    #pragma unroll
    for (int c = 0; c < C_; ++c) acc[c] = 0.f;

    if (wg < D_) {
        const int pi = i - (wg - R_);
        const int cpi = pi < 0 ? 0 : (pi > N_ - 1 ? N_ - 1 : pi);
        const float rv = (pi >= 0 && pi < N_) ? 1.f : 0.f;
        const float* Aw = Ab + (size_t)wg * D_ * NN;
        #pragma unroll
        for (int v = 0; v < D_; ++v) {
            const int pj = j - (v - R_);
            const int cpj = pj < 0 ? 0 : (pj > N_ - 1 ? N_ - 1 : pj);
            const float vv = (pj >= 0 && pj < N_) ? rv : 0.f;
            const int p = cpi * N_ + cpj;
            const float a = vv * Aw[(size_t)v * NN + p];
            #pragma unroll
            for (int c = 0; c < C_; ++c)
                acc[c] += a * xb[(size_t)c * NN + p];
        }
    }

    // stage per-wg partials
    float* rbase = red + (wg * GQ + qh) * RSTR;
    #pragma unroll
    for (int c = 0; c < C_; ++c) rbase[c] = acc[c];
    __syncthreads();

    // reduce 8 planes, store contiguous (GQ*21 = 672 floats)
    float* ob = out + ((size_t)b * NN + q0) * C_;
    for (int e = tid; e < GQ * C_; e += 256) {
        const int qq = e / C_, cc = e - qq * C_;
        const int a = qq * RSTR + cc;
        float s = 0.f;
        #pragma unroll
        for (int pl = 0; pl < 8; ++pl)
            s += red[pl * GQ * RSTR + a];
        ob[e] = s;
    }
}

extern "C" void kernel_launch(void* const* d_in, const int* in_sizes, int n_in,
                              void* d_out, int out_size, void* d_ws, size_t ws_size,
                              hipStream_t stream) {
    const float* feats = (const float*)d_in[0];   // [B,K,N,N]
    const float* x2    = (const float*)d_in[1];   // [B,C,NN]
    const int*   mask  = (const int*)d_in[2];     // [B,N,N]
    const float* cp    = (const float*)d_in[3];   // [K]
    float* out = (float*)d_out;

    float* Aarr = (float*)d_ws;                   // [B,W,NN] fp32
    const size_t Abytes = (size_t)B_ * W_ * NN * sizeof(float);

    (void)hipMemsetAsync(Aarr, 0, Abytes, stream);

    dim3 gridA(64, KC, B_);
    rwn_affinity<<<gridA, 256, 0, stream>>>(feats, mask, cp, Aarr);

    dim3 gridG(NN / GQ, B_);
    rwn_gather<<<gridG, 256, 0, stream>>>(Aarr, x2, out);
}